// Round 17
// baseline (4422.078 us; speedup 1.0000x reference)
//
#include <hip/hip_runtime.h>
#include <hip/hip_bf16.h>
#include <math.h>

// Problem constants
#define NBR 4      // branches
#define BB 8       // batch
#define NAA 128    // N*A
#define T_IN 200   // input T
#define CCH 8      // channels
#define NQ 8       // quantizers
#define NV 8192    // codebook size
#define DD 200     // feature dim (25*8)
#define ROWS 1024  // B*NA per branch
#define NKG 28     // KPAD/8 k-groups
#define CBQSH ((size_t)NBR*NKG*NV*8)   // shorts per q-plane of converted codebook

typedef __attribute__((ext_vector_type(8))) short short8;
typedef __attribute__((ext_vector_type(4))) float f32x4;

__device__ __forceinline__ unsigned short f2bf(float x) {
  unsigned u = __float_as_uint(x);
  unsigned r = (u + 0x7fffu + ((u >> 16) & 1u)) >> 16;
  return (unsigned short)r;
}
__device__ __forceinline__ bool lexlt(float av, int ai, float bv, int bi) {
  return (av < bv) || (av == bv && ai < bi);
}
__device__ __forceinline__ unsigned umn(unsigned a, unsigned b) { return a < b ? a : b; }
__device__ __forceinline__ unsigned umx(unsigned a, unsigned b) { return a > b ? a : b; }
// monotone sortkey: (score asc, idx asc) -> u32 asc; low 13 bits = idx
__device__ __forceinline__ unsigned skey(float s, int idx) {
  unsigned u = __float_as_uint(s);
  unsigned mask = ((unsigned)((int)u >> 31)) | 0x80000000u;
  return ((u ^ mask) & 0xFFFFE000u) | (unsigned)idx;
}
// async global->LDS, 16B per lane; LDS dest wave-uniform base (HW adds lane*16)
__device__ __forceinline__ void gld16(const short* g, short* s) {
  __builtin_amdgcn_global_load_lds(
      (const __attribute__((address_space(1))) unsigned*)g,
      (__attribute__((address_space(3))) unsigned*)s, 16, 0, 0);
}

// ---------------- shared cvt body ----------------
__device__ __forceinline__ void cvt_body(
    int cvtblk, int q0, const float* __restrict__ cbs,
    short* __restrict__ dh, float* __restrict__ cbn, short (*S)[65][8])
{
  const int vt = cvtblk & 127;
  const int t  = cvtblk >> 7;        // 0..15
  const int br = t >> 2, qr = t & 3;
  const int q = q0 + qr;
  const int tid = threadIdx.x;
  const int row = tid >> 2, fq = tid & 3;
  const int v0 = vt*64;
  const float* srow = cbs + ((size_t)(br*NQ + q)*NV + v0 + row)*DD;

  float s = 0.f;
  for (int j = 0; j < 13; ++j) {
    int f4 = fq + 4*j;
    if (f4 < 50) {
      float4 f = *(const float4*)&srow[4*f4];
      s += f.x*f.x + f.y*f.y + f.z*f.z + f.w*f.w;
      *(short4*)&S[f4>>1][row][(f4&1)*4] =
          make_short4((short)f2bf(f.x), (short)f2bf(f.y),
                      (short)f2bf(f.z), (short)f2bf(f.w));
    }
  }
  s += __shfl_xor(s, 1);
  s += __shfl_xor(s, 2);
  if (fq == 0) cbn[(size_t)(br*NQ + q)*NV + v0 + row] = s;
  __syncthreads();

  short* dq = dh + (size_t)q*CBQSH;
  for (int u = tid; u < NKG*64*2; u += 256) {
    int kg = u >> 7;
    int rem = u & 127;
    int v = rem >> 1, pos = (rem & 1)*4;
    short4 val = (kg < 25) ? *(const short4*)&S[kg][v][pos]
                           : make_short4(0,0,0,0);
    *(short4*)&dq[(((size_t)br*NKG + kg)*NV + v0 + v)*8 + pos] = val;
  }
}

// ---------------- conv1 stats body ----------------
template<int K>
__device__ __forceinline__ void conv1_stats_body(
    const float* __restrict__ sx, const float* __restrict__ wr, float bias,
    int tl, double& s, double& s2)
{
  constexpr int pad = (K-1)/2;
  if (tl < 25) {
    int t0 = 8*tl;
    float xw[K+7];
    #pragma unroll
    for (int i = 0; i < K+7; ++i) {
      int xi = t0 - pad + i;
      xw[i] = ((unsigned)xi < (unsigned)T_IN) ? sx[xi] : 0.f;
    }
    #pragma unroll
    for (int m = 0; m < 8; ++m) {
      float acc = bias;
      #pragma unroll
      for (int k = 0; k < K; ++k)
        acc = fmaf(wr[k], xw[m + k], acc);
      s += acc; s2 += (double)acc * acc;
    }
  }
}

// ---------------- K1 (fused): conv1 stats partials + cvt q0..3 ----------------
__global__ __launch_bounds__(256) void k_front1(
    const float* __restrict__ x,
    const float* __restrict__ w11, const float* __restrict__ w12,
    const float* __restrict__ w13, const float* __restrict__ w14,
    const float* __restrict__ b1,
    double* __restrict__ partS, double* __restrict__ partQ,
    const float* __restrict__ cbs, short* __restrict__ dh,
    float* __restrict__ cbn)
{
  __shared__ float sx[T_IN];
  __shared__ double rs[256], rq[256];
  __shared__ short S[25][65][8];
  const int bid = blockIdx.x;
  const int tid = threadIdx.x;

  if (bid >= 4096) {
    cvt_body(bid - 4096, 0, cbs, dh, cbn, S);
    return;
  }

  const int br = bid >> 10;
  const int b  = (bid >> 7) & 7;
  const int na = bid & 127;
  const int c  = tid >> 5;
  const int tl = tid & 31;
  const float* w = (br==0) ? w11 : (br==1) ? w12 : (br==2) ? w13 : w14;

  if (tid < T_IN) sx[tid] = x[((size_t)b*NAA + na)*T_IN + tid];
  __syncthreads();

  const float bias = b1[br*CCH + c];
  double s = 0.0, s2 = 0.0;
  switch (br) {
    case 0: conv1_stats_body<21>(sx, w + c*21, bias, tl, s, s2); break;
    case 1: conv1_stats_body<15>(sx, w + c*15, bias, tl, s, s2); break;
    case 2: conv1_stats_body<9> (sx, w + c*9,  bias, tl, s, s2); break;
    default: conv1_stats_body<5>(sx, w + c*5,  bias, tl, s, s2); break;
  }
  rs[tid] = s; rq[tid] = s2;
  __syncthreads();
  for (int off = 32; off > 0; off >>= 1) {
    if ((tid & 63) < off) { rs[tid] += rs[tid+off]; rq[tid] += rq[tid+off]; }
    __syncthreads();
  }
  if ((tid & 63) == 0) {
    int g = tid >> 6;
    int pi = (((br*BB + b)*4 + g) << 7) + na;
    partS[pi] = rs[tid]; partQ[pi] = rq[tid];
  }
}

// ---------------- standalone conv1 stats (small-ws fallback) ----------------
__global__ __launch_bounds__(256) void k_conv1_stats(
    const float* __restrict__ x,
    const float* __restrict__ w11, const float* __restrict__ w12,
    const float* __restrict__ w13, const float* __restrict__ w14,
    const float* __restrict__ b1,
    double* __restrict__ partS, double* __restrict__ partQ)
{
  const int bid = blockIdx.x;
  const int br = bid >> 10;
  const int b  = (bid >> 7) & 7;
  const int na = bid & 127;
  const int tid = threadIdx.x;
  const int c  = tid >> 5;
  const int tl = tid & 31;
  const float* w = (br==0) ? w11 : (br==1) ? w12 : (br==2) ? w13 : w14;

  __shared__ float sx[T_IN];
  if (tid < T_IN) sx[tid] = x[((size_t)b*NAA + na)*T_IN + tid];
  __syncthreads();

  const float bias = b1[br*CCH + c];
  double s = 0.0, s2 = 0.0;
  switch (br) {
    case 0: conv1_stats_body<21>(sx, w + c*21, bias, tl, s, s2); break;
    case 1: conv1_stats_body<15>(sx, w + c*15, bias, tl, s, s2); break;
    case 2: conv1_stats_body<9> (sx, w + c*9,  bias, tl, s, s2); break;
    default: conv1_stats_body<5>(sx, w + c*5,  bias, tl, s, s2); break;
  }
  __shared__ double rs[256], rq[256];
  rs[tid] = s; rq[tid] = s2;
  __syncthreads();
  for (int off = 32; off > 0; off >>= 1) {
    if ((tid & 63) < off) { rs[tid] += rs[tid+off]; rq[tid] += rq[tid+off]; }
    __syncthreads();
  }
  if ((tid & 63) == 0) {
    int g = tid >> 6;
    int pi = (((br*BB + b)*4 + g) << 7) + na;
    partS[pi] = rs[tid]; partQ[pi] = rq[tid];
  }
}

// ---------------- K3 (fused): frontend mid + cvt q4..7 ----------------
template<int K1, int K2>
__device__ __forceinline__ void mid_body(
    const float* __restrict__ sx, float* __restrict__ sy,
    const float* __restrict__ w1, const float* __restrict__ w2,
    float bias1, float fm, float rst, float gm, float bt, float bias2,
    int c, int tl, float* __restrict__ yout, double& s, double& s2)
{
  constexpr int pad1 = (K1-1)/2, pad2 = (K2-1)/2;
  const float* wr = w1 + c*K1;
  if (tl < 25) {
    int t0 = 8*tl;
    float xw[K1+7];
    #pragma unroll
    for (int i = 0; i < K1+7; ++i) {
      int xi = t0 - pad1 + i;
      xw[i] = ((unsigned)xi < (unsigned)T_IN) ? sx[xi] : 0.f;
    }
    #pragma unroll
    for (int m = 0; m < 4; ++m) {
      float u = 0.f;
      #pragma unroll
      for (int h = 0; h < 2; ++h) {
        float acc = bias1;
        #pragma unroll
        for (int k = 0; k < K1; ++k)
          acc = fmaf(wr[k], xw[2*m + h + k], acc);
        float xn = (acc - fm) * rst * gm + bt;
        u += 0.5f * xn * (1.0f + erff(xn * 0.70710678118654752440f));
      }
      sy[c*100 + 4*tl + m] = 0.5f * u;
    }
  }
  __syncthreads();
  if (tl < 25) {
    int t0 = 4*tl;
    float a0 = bias2, a1 = bias2, a2 = bias2, a3 = bias2;
    #pragma unroll
    for (int cin = 0; cin < CCH; ++cin) {
      const float* wr2 = w2 + (c*CCH + cin)*K2;
      float wv[K2];
      #pragma unroll
      for (int k = 0; k < K2; ++k) wv[k] = wr2[k];
      float yw[K2+3];
      #pragma unroll
      for (int i = 0; i < K2+3; ++i) {
        int yi = t0 - pad2 + i;
        yw[i] = ((unsigned)yi < 100u) ? sy[cin*100 + yi] : 0.f;
      }
      #pragma unroll
      for (int k = 0; k < K2; ++k) a0 = fmaf(wv[k], yw[k], a0);
      #pragma unroll
      for (int k = 0; k < K2; ++k) a1 = fmaf(wv[k], yw[1 + k], a1);
      #pragma unroll
      for (int k = 0; k < K2; ++k) a2 = fmaf(wv[k], yw[2 + k], a2);
      #pragma unroll
      for (int k = 0; k < K2; ++k) a3 = fmaf(wv[k], yw[3 + k], a3);
    }
    *(float4*)&yout[t0] = make_float4(a0, a1, a2, a3);
    s += a0; s2 += (double)a0 * a0;
    s += a1; s2 += (double)a1 * a1;
    s += a2; s2 += (double)a2 * a2;
    s += a3; s2 += (double)a3 * a3;
  }
}

__global__ __launch_bounds__(256) void k_mid(
    const float* __restrict__ x,
    const float* __restrict__ w11, const float* __restrict__ w12,
    const float* __restrict__ w13, const float* __restrict__ w14,
    const float* __restrict__ b1, const float* __restrict__ g1,
    const float* __restrict__ be1,
    const double* __restrict__ partS1, const double* __restrict__ partQ1,
    const float* __restrict__ w21, const float* __restrict__ w22,
    const float* __restrict__ w23, const float* __restrict__ w24,
    const float* __restrict__ b2,
    float* __restrict__ y2raw,
    double* __restrict__ partS, double* __restrict__ partQ,
    const float* __restrict__ cbs, short* __restrict__ dh,
    float* __restrict__ cbn)
{
  __shared__ float sx[T_IN];
  __shared__ float sy[CCH*100];
  __shared__ float sstat[8];
  __shared__ double rs[256], rq[256];
  __shared__ short S[25][65][8];

  const int bid = blockIdx.x;
  const int tid = threadIdx.x;

  if (bid >= 4096) {
    cvt_body(bid - 4096, 4, cbs, dh, cbn, S);
    return;
  }

  const int br = bid >> 10;
  const int b  = (bid >> 7) & 7;
  const int na = bid & 127;
  const int c  = tid >> 5;
  const int tl = tid & 31;
  const int wid = tid >> 6;
  const int l = tid & 63;
  const float* w1 = (br==0) ? w11 : (br==1) ? w12 : (br==2) ? w13 : w14;
  const float* w2 = (br==0) ? w21 : (br==1) ? w22 : (br==2) ? w23 : w24;

  if (tid < T_IN) sx[tid] = x[((size_t)b*NAA + na)*T_IN + tid];

  {
    int base = (((br*BB + b)*4 + wid) << 7);
    double a  = partS1[base + l] + partS1[base + 64 + l];
    double qn = partQ1[base + l] + partQ1[base + 64 + l];
    #pragma unroll
    for (int m = 32; m >= 1; m >>= 1) {
      a  += __shfl_xor(a, m);
      qn += __shfl_xor(qn, m);
    }
    if (l == 0) {
      double mean = a / 51200.0;            // 2*128*200
      double var  = qn / 51200.0 - mean*mean;
      sstat[wid*2]     = (float)mean;
      sstat[wid*2 + 1] = (float)(1.0 / sqrt(var + 1e-5));
    }
  }
  __syncthreads();

  const float bias1 = b1[br*CCH + c];
  const float fm  = sstat[(c>>1)*2];
  const float rst = sstat[(c>>1)*2 + 1];
  const float gm = g1[br*CCH + c], bt = be1[br*CCH + c];
  const float bias2 = b2[br*CCH + c];
  float* yout = y2raw + ((((size_t)br*BB + b)*CCH + c)*NAA + na)*100;

  double s = 0.0, s2 = 0.0;
  switch (br) {
    case 0: mid_body<21,9>(sx, sy, w1, w2, bias1, fm, rst, gm, bt, bias2, c, tl, yout, s, s2); break;
    case 1: mid_body<15,7>(sx, sy, w1, w2, bias1, fm, rst, gm, bt, bias2, c, tl, yout, s, s2); break;
    case 2: mid_body<9,5> (sx, sy, w1, w2, bias1, fm, rst, gm, bt, bias2, c, tl, yout, s, s2); break;
    default: mid_body<5,3>(sx, sy, w1, w2, bias1, fm, rst, gm, bt, bias2, c, tl, yout, s, s2); break;
  }

  rs[tid] = s; rq[tid] = s2;
  __syncthreads();
  for (int off = 32; off > 0; off >>= 1) {
    if ((tid & 63) < off) { rs[tid] += rs[tid+off]; rq[tid] += rq[tid+off]; }
    __syncthreads();
  }
  if ((tid & 63) == 0) {
    int g = tid >> 6;
    int pi = (((br*BB + b)*4 + g) << 7) + na;
    partS[pi] = rs[tid]; partQ[pi] = rq[tid];
  }
}

// ---------------- K5: inline stats2 + GN2 + GELU + pool4 + transpose (+ padzero + qcnt zero) ----------------
__global__ __launch_bounds__(256) void k_tail(
    const float* __restrict__ y2raw, const float* __restrict__ g2,
    const float* __restrict__ be2,
    const double* __restrict__ partS2, const double* __restrict__ partQ2,
    float* __restrict__ res, short* __restrict__ resh, int* __restrict__ qcnt)
{
  const int tid = threadIdx.x;
  int idx = blockIdx.x * 256 + tid;
  int c  = idx & 7;
  int tp = (idx >> 3) % 25;
  int na = (idx / 200) & 127;
  int b  = (idx / 25600) & 7;
  int br = idx / 204800;
  const int wid = tid >> 6, l = tid & 63;

  if (blockIdx.x == 0) qcnt[tid] = 0;   // NQ*32 = 256 counters

  if (idx < NBR*3*ROWS*8) {
    int pos = idx & 7;
    int prow = (idx >> 3) & 1023;
    int r2  = idx >> 13;
    int pbr = r2 / 3, kgp = r2 - pbr*3;
    resh[(((size_t)pbr*NKG + 25 + kgp)*ROWS + prow)*8 + pos] = 0;
  }

  __shared__ float sstat[8];
  {
    int base = (((br*BB + b)*4 + wid) << 7);
    double a  = partS2[base + l] + partS2[base + 64 + l];
    double qn = partQ2[base + l] + partQ2[base + 64 + l];
    #pragma unroll
    for (int m = 32; m >= 1; m >>= 1) {
      a  += __shfl_xor(a, m);
      qn += __shfl_xor(qn, m);
    }
    if (l == 0) {
      double mean = a / 25600.0;            // 2*128*100
      double var  = qn / 25600.0 - mean*mean;
      sstat[wid*2]     = (float)mean;
      sstat[wid*2 + 1] = (float)(1.0 / sqrt(var + 1e-5));
    }
  }
  __syncthreads();

  int g = c >> 1;
  float fm  = sstat[g*2];
  float rst = sstat[g*2 + 1];
  float gm = g2[br*CCH + c], bt = be2[br*CCH + c];
  float4 v = *(const float4*)&y2raw[((((size_t)br*BB + b)*CCH + c)*NAA + na)*100 + 4*tp];
  float sum4 = 0.f;
  #pragma unroll
  for (int h = 0; h < 4; ++h) {
    float xv = (h==0) ? v.x : (h==1) ? v.y : (h==2) ? v.z : v.w;
    float xn = (xv - fm) * rst * gm + bt;
    sum4 += 0.5f * xn * (1.0f + erff(xn * 0.70710678118654752440f));
  }
  float val = 0.25f * sum4;
  int row = b*NAA + na;
  res[((size_t)br*ROWS + row)*DD + tp*8 + c] = val;
  resh[(((size_t)br*NKG + tp)*ROWS + row)*8 + c] = (short)f2bf(val);
}

// ---------------- standalone cvt (small-ws fallback, one q) ----------------
__global__ __launch_bounds__(256) void k_cvt_cb(
    const float* __restrict__ cbs, int q,
    short* __restrict__ dh, float* __restrict__ cbn)
{
  __shared__ short S[25][65][8];
  const int blk = blockIdx.x;
  const int vt = blk & 127;
  const int br = blk >> 7;
  const int tid = threadIdx.x;
  const int row = tid >> 2, fq = tid & 3;
  const int v0 = vt*64;
  const float* srow = cbs + ((size_t)(br*NQ + q)*NV + v0 + row)*DD;

  float s = 0.f;
  for (int j = 0; j < 13; ++j) {
    int f4 = fq + 4*j;
    if (f4 < 50) {
      float4 f = *(const float4*)&srow[4*f4];
      s += f.x*f.x + f.y*f.y + f.z*f.z + f.w*f.w;
      *(short4*)&S[f4>>1][row][(f4&1)*4] =
          make_short4((short)f2bf(f.x), (short)f2bf(f.y),
                      (short)f2bf(f.z), (short)f2bf(f.w));
    }
  }
  s += __shfl_xor(s, 1);
  s += __shfl_xor(s, 2);
  if (fq == 0) cbn[(size_t)(br*NQ + q)*NV + v0 + row] = s;
  __syncthreads();

  for (int u = tid; u < NKG*64*2; u += 256) {
    int kg = u >> 7;
    int rem = u & 127;
    int v = rem >> 1, pos = (rem & 1)*4;
    short4 val = (kg < 25) ? *(const short4*)&S[kg][v][pos]
                           : make_short4(0,0,0,0);
    *(short4*)&dh[(((size_t)br*NKG + kg)*NV + v0 + v)*8 + pos] = val;
  }
}

// ================= gemm tile body =================
__device__ __forceinline__ void gemm_tile(
    int p, const short* __restrict__ resh, const short* __restrict__ cbh_q,
    const float* __restrict__ cbn, int q, unsigned* __restrict__ candk,
    short (*S)[4][130][8])
{
  const int x = p & 7;
  const int sIdx = p >> 3;
  const int br = sIdx >> 6;
  const int rb = (sIdx >> 3) & 7;
  const int vb = x*8 + (sIdx & 7);
  const int tid = threadIdx.x;
  const int w = tid >> 6;
  const int l = tid & 63;
  const int wr = w >> 1, wc = w & 1;
  const int kgl = l >> 4, fr = l & 15;

  f32x4 acc[4][4];
  #pragma unroll
  for (int i = 0; i < 4; ++i)
    #pragma unroll
    for (int j = 0; j < 4; ++j)
      acc[i][j] = (f32x4){0.f, 0.f, 0.f, 0.f};

  short8 aA[2][4];

  #define STAGE(nb, ks)                                                           \
    {                                                                             \
      _Pragma("unroll")                                                           \
      for (int i = 0; i < 4; ++i)                                                 \
        aA[nb][i] = *(const short8*)&resh[                                        \
          (((size_t)br*NKG + (ks)*4 + kgl)*ROWS + rb*128 + wr*64 + i*16 + fr)*8]; \
      _Pragma("unroll")                                                           \
      for (int t = 0; t < 2; ++t) {                                               \
        int u = (w << 1) | t;                                                     \
        int kg = u >> 1, wh = u & 1;                                              \
        gld16(cbh_q + (((size_t)br*NKG + (ks)*4 + kg)*NV + vb*128 + wh*64 + l)*8, \
              &S[nb][kg][wh*64][0]);                                              \
      }                                                                           \
    }

  STAGE(0, 0);

  #pragma unroll
  for (int ks = 0; ks < 7; ++ks) {
    const int cur = ks & 1, nxt = cur ^ 1;
    if (ks < 6) {
      STAGE(nxt, ks + 1);
      asm volatile("s_waitcnt vmcnt(6)" ::: "memory");
    } else {
      asm volatile("s_waitcnt vmcnt(0)" ::: "memory");
    }
    __builtin_amdgcn_s_barrier();

    short8 bh[4];
    #pragma unroll
    for (int j = 0; j < 4; ++j)
      bh[j] = *(const short8*)&S[cur][kgl][wc*64 + j*16 + fr][0];
    #pragma unroll
    for (int i = 0; i < 4; ++i)
      #pragma unroll
      for (int j = 0; j < 4; ++j)
        acc[i][j] = __builtin_amdgcn_mfma_f32_16x16x32_bf16(aA[cur][i], bh[j], acc[i][j], 0, 0, 0);

    asm volatile("" ::: "memory");
    __builtin_amdgcn_s_barrier();
  }
  #undef STAGE

  const float* cn = cbn + (size_t)(br*NQ + q)*NV;
  float nj[4]; int vgj[4];
  #pragma unroll
  for (int j = 0; j < 4; ++j) {
    vgj[j] = vb*128 + wc*64 + j*16 + fr;
    nj[j] = 0.5f * cn[vgj[j]];
  }
  #pragma unroll
  for (int i = 0; i < 4; ++i) {
    #pragma unroll
    for (int reg = 0; reg < 4; ++reg) {
      unsigned k0 = skey(nj[0] - acc[i][0][reg], vgj[0]);
      unsigned k1 = skey(nj[1] - acc[i][1][reg], vgj[1]);
      unsigned k2 = skey(nj[2] - acc[i][2][reg], vgj[2]);
      unsigned k3 = skey(nj[3] - acc[i][3][reg], vgj[3]);
      unsigned a = umn(k0, k1), b = umx(k0, k1);
      unsigned c = umn(k2, k3), d = umx(k2, k3);
      unsigned c1 = umn(a, c);
      unsigned c2 = umn(umx(a, c), umn(b, d));
      #pragma unroll
      for (int m = 1; m <= 8; m <<= 1) {
        unsigned o1 = __shfl_xor(c1, m);
        unsigned o2 = __shfl_xor(c2, m);
        unsigned t = umx(c1, o1);
        c1 = umn(c1, o1);
        c2 = umn(umn(t, c2), o2);
      }
      if (fr == 0) {
        int grow = br*ROWS + rb*128 + wr*64 + i*16 + kgl*4 + reg;
        size_t o = ((size_t)grow*64 + vb)*4 + wc*2;
        candk[o] = c1; candk[o+1] = c2;
      }
    }
  }
}

// ================= update wave body =================
__device__ __forceinline__ void update_row(
    int r, const float* __restrict__ cbs, const float* __restrict__ cbn,
    const unsigned* __restrict__ candk, float* __restrict__ res,
    float* __restrict__ outq, float* __restrict__ outi,
    short* __restrict__ resh, int q, int lane)
{
  const int br = r >> 10;
  const int row = r & 1023;

  const unsigned* ck = candk + (size_t)r * 256;
  uint4 kk = *(const uint4*)&ck[4*lane];
  unsigned c0 = kk.x, c1 = kk.y, c2 = kk.z, c3 = kk.w;

  unsigned mykey = 0xFFFFFFFFu;
  #pragma unroll
  for (int t = 0; t < 8; ++t) {
    unsigned lm = umn(umn(c0, c1), umn(c2, c3));
    #pragma unroll
    for (int m = 1; m <= 32; m <<= 1)
      lm = umn(lm, __shfl_xor(lm, m));
    if (c0 == lm) c0 = 0xFFFFFFFFu;
    if (c1 == lm) c1 = 0xFFFFFFFFu;
    if (c2 == lm) c2 = 0xFFFFFFFFu;
    if (c3 == lm) c3 = 0xFFFFFFFFu;
    if ((lane >> 3) == t) mykey = lm;
  }
  const int mycand = (int)(mykey & 0x1FFFu);

  const int kl = lane & 7;
  const float* cbrow = cbs + ((size_t)(br*NQ + q)*NV + mycand)*DD;
  const float* rrow0 = res + (size_t)r*DD;
  float dot = 0.f;
  #pragma unroll
  for (int u = 0; u < 7; ++u) {
    int f4 = kl + 8*u;
    if (f4 < 50) {
      float4 r4 = *(const float4*)&rrow0[4*f4];
      float4 c4 = *(const float4*)&cbrow[4*f4];
      dot = fmaf(r4.x, c4.x, dot);
      dot = fmaf(r4.y, c4.y, dot);
      dot = fmaf(r4.z, c4.z, dot);
      dot = fmaf(r4.w, c4.w, dot);
    }
  }
  dot += __shfl_xor(dot, 1);
  dot += __shfl_xor(dot, 2);
  dot += __shfl_xor(dot, 4);
  float dist = fmaf(-2.f, dot, cbn[(size_t)(br*NQ + q)*NV + mycand]);

  float bv = dist; int bi = mycand;
  #pragma unroll
  for (int m = 8; m <= 32; m <<= 1) {
    float ov = __shfl_xor(bv, m); int oi = __shfl_xor(bi, m);
    if (lexlt(ov, oi, bv, bi)) { bv = ov; bi = oi; }
  }

  if (lane == 0)
    outi[(((size_t)br*NQ + q)*BB + (row >> 7))*NAA + (row & 127)] = (float)bi;

  const float* c = cbs + ((size_t)(br*NQ + q)*NV + bi)*DD;
  float* rrow = res  + ((size_t)br*ROWS + row)*DD;
  float* qrow = outq + ((size_t)br*ROWS + row)*DD;
  if (lane < 50) {
    float4 cvv = *(const float4*)&c[4*lane];
    float4 r4 = *(const float4*)&rrow[4*lane];
    r4.x -= cvv.x; r4.y -= cvv.y; r4.z -= cvv.z; r4.w -= cvv.w;
    *(float4*)&rrow[4*lane] = r4;
    float4 qv;
    if (q == 0) {
      qv = cvv;
    } else {
      qv = *(const float4*)&qrow[4*lane];
      qv.x += cvv.x; qv.y += cvv.y; qv.z += cvv.z; qv.w += cvv.w;
    }
    *(float4*)&qrow[4*lane] = qv;

    *(short4*)&resh[(((size_t)br*NKG + (lane>>1))*ROWS + row)*8 + (lane&1)*4] =
        make_short4((short)f2bf(r4.x), (short)f2bf(r4.y),
                    (short)f2bf(r4.z), (short)f2bf(r4.w));
  }
}

// ---------------- fused gemm + last-block update (one dispatch per q) ----------------
__global__ __launch_bounds__(256) void k_gemmu(
    short* __restrict__ resh, const short* __restrict__ cbh_q,
    const float* __restrict__ cbn, int q, unsigned* __restrict__ candk,
    const float* __restrict__ cbs, float* __restrict__ res,
    float* __restrict__ outq, float* __restrict__ outi,
    int* __restrict__ qcnt)
{
  __shared__ short S[2][4][130][8];
  __shared__ int sLast;

  gemm_tile(blockIdx.x, resh, cbh_q, cbn, q, candk, S);

  const int p = blockIdx.x;
  const int sIdx = p >> 3;
  const int br = sIdx >> 6;
  const int rb = (sIdx >> 3) & 7;
  const int tid = threadIdx.x;

  // release: make this block's candk writes visible, then count in
  __threadfence();
  __syncthreads();
  if (tid == 0) {
    int old = atomicAdd(&qcnt[q*32 + br*8 + rb], 1);
    sLast = (old == 63) ? 1 : 0;
  }
  __syncthreads();

  if (sLast) {
    __threadfence();   // acquire: see all 64 blocks' candk writes
    const int wid = tid >> 6, lane = tid & 63;
    #pragma unroll 1
    for (int rr = 0; rr < 32; ++rr) {
      int r = br*ROWS + rb*128 + rr*4 + wid;
      update_row(r, cbs, cbn, candk, res, outq, outi, resh, q, lane);
    }
  }
}

// ---------------- standalone gemm / update (small-ws fallback path) ----------------
__global__ __launch_bounds__(256) void k_gemm(
    const short* __restrict__ resh, const short* __restrict__ cbh,
    const float* __restrict__ cbn, int q,
    unsigned* __restrict__ candk)
{
  __shared__ short S[2][4][130][8];
  gemm_tile(blockIdx.x, resh, cbh, cbn, q, candk, S);
}

__global__ __launch_bounds__(256) void k_update3(
    const float* __restrict__ cbs, const float* __restrict__ cbn,
    const unsigned* __restrict__ candk,
    float* __restrict__ res, float* __restrict__ outq,
    float* __restrict__ outi, short* __restrict__ resh, int q)
{
  const int wid = threadIdx.x >> 6;
  const int lane = threadIdx.x & 63;
  update_row(blockIdx.x*4 + wid, cbs, cbn, candk, res, outq, outi, resh, q, lane);
}

extern "C" void kernel_launch(void* const* d_in, const int* in_sizes, int n_in,
                              void* d_out, int out_size, void* d_ws, size_t ws_size,
                              hipStream_t stream)
{
  const float* x   = (const float*)d_in[0];
  const float* w11 = (const float*)d_in[1];
  const float* w12 = (const float*)d_in[2];
  const float* w13 = (const float*)d_in[3];
  const float* w14 = (const float*)d_in[4];
  const float* b1  = (const float*)d_in[5];
  const float* g1  = (const float*)d_in[6];
  const float* be1 = (const float*)d_in[7];
  const float* w21 = (const float*)d_in[8];
  const float* w22 = (const float*)d_in[9];
  const float* w23 = (const float*)d_in[10];
  const float* w24 = (const float*)d_in[11];
  const float* b2  = (const float*)d_in[12];
  const float* g2  = (const float*)d_in[13];
  const float* be2 = (const float*)d_in[14];
  const float* cbs = (const float*)d_in[15];

  // workspace layout
  char* wsb = (char*)d_ws;
  double* partS1 = (double*)wsb;
  double* partQ1 = partS1 + 16384;
  double* partS2 = partQ1 + 16384;
  double* partQ2 = partS2 + 16384;
  float* fbase = (float*)(partQ2 + 16384);
  float* y2raw = fbase;                                // 3,276,800
  float* res   = y2raw + 3276800;                      // 819,200
  float* cbn   = res + 819200;                         // 262,144
  unsigned* candk = (unsigned*)(cbn + 262144);         // 1,048,576 u32
  short* resh  = (short*)(candk + 1048576);            // 917,504 shorts
  int*   qcnt  = (int*)(resh + 917504);                // 256 ints
  short* cbh   = (short*)(qcnt + 256);                 // CBQSH * (big ? 8 : 1)
  const size_t base_bytes = (char*)cbh - wsb;
  const bool big = ws_size >= base_bytes + CBQSH*8*sizeof(short) + 1024;

  float* outq = (float*)d_out;         // [4][8][128][200]
  float* outi = outq + 819200;         // [4][8][8][128] (float-encoded indices)

  // frontend (+ cvt overlapped when big)
  if (big) {
    k_front1<<<4096 + 2048, 256, 0, stream>>>(x, w11, w12, w13, w14, b1,
                                              partS1, partQ1, cbs, cbh, cbn);
    k_mid<<<4096 + 2048, 256, 0, stream>>>(x, w11, w12, w13, w14, b1, g1, be1,
                                           partS1, partQ1,
                                           w21, w22, w23, w24, b2, y2raw,
                                           partS2, partQ2, cbs, cbh, cbn);
  } else {
    k_conv1_stats<<<4096, 256, 0, stream>>>(x, w11, w12, w13, w14, b1, partS1, partQ1);
    k_mid<<<4096, 256, 0, stream>>>(x, w11, w12, w13, w14, b1, g1, be1,
                                    partS1, partQ1,
                                    w21, w22, w23, w24, b2, y2raw,
                                    partS2, partQ2, cbs, cbh, cbn);
  }
  k_tail<<<3200, 256, 0, stream>>>(y2raw, g2, be2, partS2, partQ2, res, resh, qcnt);

  if (big) {
    // one fused dispatch per q: gemm + last-block-of-group update
    for (int q = 0; q < NQ; ++q)
      k_gemmu<<<2048, 256, 0, stream>>>(resh, cbh + (size_t)q*CBQSH, cbn, q,
                                        candk, cbs, res, outq, outi, qcnt);
  } else {
    for (int q = 0; q < NQ; ++q) {
      k_cvt_cb<<<NBR*128, 256, 0, stream>>>(cbs, q, cbh, cbn);
      k_gemm<<<2048, 256, 0, stream>>>(resh, cbh, cbn, q, candk);
      k_update3<<<1024, 256, 0, stream>>>(cbs, cbn, candk, res, outq, outi, resh, q);
    }
  }
}

// Round 18
// 426.918 us; speedup vs baseline: 10.3582x; 10.3582x over previous
//
#include <hip/hip_runtime.h>
#include <hip/hip_bf16.h>
#include <math.h>

// Problem constants
#define NBR 4      // branches
#define BB 8       // batch
#define NAA 128    // N*A
#define T_IN 200   // input T
#define CCH 8      // channels
#define NQ 8       // quantizers
#define NV 8192    // codebook size
#define DD 200     // feature dim (25*8)
#define ROWS 1024  // B*NA per branch
#define NKG 28     // KPAD/8 k-groups
#define CBQSH ((size_t)NBR*NKG*NV*8)   // shorts per q-plane of converted codebook

typedef __attribute__((ext_vector_type(8))) short short8;
typedef __attribute__((ext_vector_type(4))) float f32x4;

__device__ __forceinline__ unsigned short f2bf(float x) {
  unsigned u = __float_as_uint(x);
  unsigned r = (u + 0x7fffu + ((u >> 16) & 1u)) >> 16;
  return (unsigned short)r;
}
__device__ __forceinline__ bool lexlt(float av, int ai, float bv, int bi) {
  return (av < bv) || (av == bv && ai < bi);
}
__device__ __forceinline__ unsigned umn(unsigned a, unsigned b) { return a < b ? a : b; }
__device__ __forceinline__ unsigned umx(unsigned a, unsigned b) { return a > b ? a : b; }
// monotone sortkey: (score asc, idx asc) -> u32 asc; low 13 bits = idx
__device__ __forceinline__ unsigned skey(float s, int idx) {
  unsigned u = __float_as_uint(s);
  unsigned mask = ((unsigned)((int)u >> 31)) | 0x80000000u;
  return ((u ^ mask) & 0xFFFFE000u) | (unsigned)idx;
}
// async global->LDS, 16B per lane; LDS dest wave-uniform base (HW adds lane*16)
__device__ __forceinline__ void gld16(const short* g, short* s) {
  __builtin_amdgcn_global_load_lds(
      (const __attribute__((address_space(1))) unsigned*)g,
      (__attribute__((address_space(3))) unsigned*)s, 16, 0, 0);
}

// ---------------- shared cvt body: 64 codewords of (br,q) -> bf16 k-major + norms ----------------
__device__ __forceinline__ void cvt_body(
    int cvtblk, int q0, const float* __restrict__ cbs,
    short* __restrict__ dh, float* __restrict__ cbn, short (*S)[65][8])
{
  const int vt = cvtblk & 127;
  const int t  = cvtblk >> 7;        // 0..15
  const int br = t >> 2, qr = t & 3;
  const int q = q0 + qr;
  const int tid = threadIdx.x;
  const int row = tid >> 2, fq = tid & 3;
  const int v0 = vt*64;
  const float* srow = cbs + ((size_t)(br*NQ + q)*NV + v0 + row)*DD;

  float s = 0.f;
  for (int j = 0; j < 13; ++j) {
    int f4 = fq + 4*j;
    if (f4 < 50) {
      float4 f = *(const float4*)&srow[4*f4];
      s += f.x*f.x + f.y*f.y + f.z*f.z + f.w*f.w;
      *(short4*)&S[f4>>1][row][(f4&1)*4] =
          make_short4((short)f2bf(f.x), (short)f2bf(f.y),
                      (short)f2bf(f.z), (short)f2bf(f.w));
    }
  }
  s += __shfl_xor(s, 1);
  s += __shfl_xor(s, 2);
  if (fq == 0) cbn[(size_t)(br*NQ + q)*NV + v0 + row] = s;
  __syncthreads();

  short* dq = dh + (size_t)q*CBQSH;
  for (int u = tid; u < NKG*64*2; u += 256) {
    int kg = u >> 7;
    int rem = u & 127;
    int v = rem >> 1, pos = (rem & 1)*4;
    short4 val = (kg < 25) ? *(const short4*)&S[kg][v][pos]
                           : make_short4(0,0,0,0);
    *(short4*)&dq[(((size_t)br*NKG + kg)*NV + v0 + v)*8 + pos] = val;
  }
}

// ---------------- conv1 stats body (8-consecutive-t windows) ----------------
template<int K>
__device__ __forceinline__ void conv1_stats_body(
    const float* __restrict__ sx, const float* __restrict__ wr, float bias,
    int tl, double& s, double& s2)
{
  constexpr int pad = (K-1)/2;
  if (tl < 25) {
    int t0 = 8*tl;
    float xw[K+7];
    #pragma unroll
    for (int i = 0; i < K+7; ++i) {
      int xi = t0 - pad + i;
      xw[i] = ((unsigned)xi < (unsigned)T_IN) ? sx[xi] : 0.f;
    }
    #pragma unroll
    for (int m = 0; m < 8; ++m) {
      float acc = bias;
      #pragma unroll
      for (int k = 0; k < K; ++k)
        acc = fmaf(wr[k], xw[m + k], acc);
      s += acc; s2 += (double)acc * acc;
    }
  }
}

// ---------------- K1 (fused): conv1 stats partials + cvt q0..3 ----------------
__global__ __launch_bounds__(256) void k_front1(
    const float* __restrict__ x,
    const float* __restrict__ w11, const float* __restrict__ w12,
    const float* __restrict__ w13, const float* __restrict__ w14,
    const float* __restrict__ b1,
    double* __restrict__ partS, double* __restrict__ partQ,
    const float* __restrict__ cbs, short* __restrict__ dh,
    float* __restrict__ cbn)
{
  __shared__ float sx[T_IN];
  __shared__ double rs[256], rq[256];
  __shared__ short S[25][65][8];
  const int bid = blockIdx.x;
  const int tid = threadIdx.x;

  if (bid >= 4096) {
    cvt_body(bid - 4096, 0, cbs, dh, cbn, S);
    return;
  }

  const int br = bid >> 10;
  const int b  = (bid >> 7) & 7;
  const int na = bid & 127;
  const int c  = tid >> 5;
  const int tl = tid & 31;
  const float* w = (br==0) ? w11 : (br==1) ? w12 : (br==2) ? w13 : w14;

  if (tid < T_IN) sx[tid] = x[((size_t)b*NAA + na)*T_IN + tid];
  __syncthreads();

  const float bias = b1[br*CCH + c];
  double s = 0.0, s2 = 0.0;
  switch (br) {
    case 0: conv1_stats_body<21>(sx, w + c*21, bias, tl, s, s2); break;
    case 1: conv1_stats_body<15>(sx, w + c*15, bias, tl, s, s2); break;
    case 2: conv1_stats_body<9> (sx, w + c*9,  bias, tl, s, s2); break;
    default: conv1_stats_body<5>(sx, w + c*5,  bias, tl, s, s2); break;
  }
  rs[tid] = s; rq[tid] = s2;
  __syncthreads();
  for (int off = 32; off > 0; off >>= 1) {
    if ((tid & 63) < off) { rs[tid] += rs[tid+off]; rq[tid] += rq[tid+off]; }
    __syncthreads();
  }
  if ((tid & 63) == 0) {
    int g = tid >> 6;
    int pi = (((br*BB + b)*4 + g) << 7) + na;
    partS[pi] = rs[tid]; partQ[pi] = rq[tid];
  }
}

// ---------------- standalone conv1 stats (small-ws fallback) ----------------
__global__ __launch_bounds__(256) void k_conv1_stats(
    const float* __restrict__ x,
    const float* __restrict__ w11, const float* __restrict__ w12,
    const float* __restrict__ w13, const float* __restrict__ w14,
    const float* __restrict__ b1,
    double* __restrict__ partS, double* __restrict__ partQ)
{
  const int bid = blockIdx.x;
  const int br = bid >> 10;
  const int b  = (bid >> 7) & 7;
  const int na = bid & 127;
  const int tid = threadIdx.x;
  const int c  = tid >> 5;
  const int tl = tid & 31;
  const float* w = (br==0) ? w11 : (br==1) ? w12 : (br==2) ? w13 : w14;

  __shared__ float sx[T_IN];
  if (tid < T_IN) sx[tid] = x[((size_t)b*NAA + na)*T_IN + tid];
  __syncthreads();

  const float bias = b1[br*CCH + c];
  double s = 0.0, s2 = 0.0;
  switch (br) {
    case 0: conv1_stats_body<21>(sx, w + c*21, bias, tl, s, s2); break;
    case 1: conv1_stats_body<15>(sx, w + c*15, bias, tl, s, s2); break;
    case 2: conv1_stats_body<9> (sx, w + c*9,  bias, tl, s, s2); break;
    default: conv1_stats_body<5>(sx, w + c*5,  bias, tl, s, s2); break;
  }
  __shared__ double rs[256], rq[256];
  rs[tid] = s; rq[tid] = s2;
  __syncthreads();
  for (int off = 32; off > 0; off >>= 1) {
    if ((tid & 63) < off) { rs[tid] += rs[tid+off]; rq[tid] += rq[tid+off]; }
    __syncthreads();
  }
  if ((tid & 63) == 0) {
    int g = tid >> 6;
    int pi = (((br*BB + b)*4 + g) << 7) + na;
    partS[pi] = rs[tid]; partQ[pi] = rq[tid];
  }
}

// ---------------- K3 (fused): inline stats1 + conv1 + GN1 + GELU + pool2 -> conv2 + stats2 ; + cvt q4..7 ----------------
template<int K1, int K2>
__device__ __forceinline__ void mid_body(
    const float* __restrict__ sx, float* __restrict__ sy,
    const float* __restrict__ w1, const float* __restrict__ w2,
    float bias1, float fm, float rst, float gm, float bt, float bias2,
    int c, int tl, float* __restrict__ yout, double& s, double& s2)
{
  constexpr int pad1 = (K1-1)/2, pad2 = (K2-1)/2;
  const float* wr = w1 + c*K1;
  if (tl < 25) {
    int t0 = 8*tl;
    float xw[K1+7];
    #pragma unroll
    for (int i = 0; i < K1+7; ++i) {
      int xi = t0 - pad1 + i;
      xw[i] = ((unsigned)xi < (unsigned)T_IN) ? sx[xi] : 0.f;
    }
    #pragma unroll
    for (int m = 0; m < 4; ++m) {
      float u = 0.f;
      #pragma unroll
      for (int h = 0; h < 2; ++h) {
        float acc = bias1;
        #pragma unroll
        for (int k = 0; k < K1; ++k)
          acc = fmaf(wr[k], xw[2*m + h + k], acc);
        float xn = (acc - fm) * rst * gm + bt;
        u += 0.5f * xn * (1.0f + erff(xn * 0.70710678118654752440f));
      }
      sy[c*100 + 4*tl + m] = 0.5f * u;
    }
  }
  __syncthreads();
  if (tl < 25) {
    int t0 = 4*tl;
    float a0 = bias2, a1 = bias2, a2 = bias2, a3 = bias2;
    #pragma unroll
    for (int cin = 0; cin < CCH; ++cin) {
      const float* wr2 = w2 + (c*CCH + cin)*K2;
      float wv[K2];
      #pragma unroll
      for (int k = 0; k < K2; ++k) wv[k] = wr2[k];
      float yw[K2+3];
      #pragma unroll
      for (int i = 0; i < K2+3; ++i) {
        int yi = t0 - pad2 + i;
        yw[i] = ((unsigned)yi < 100u) ? sy[cin*100 + yi] : 0.f;
      }
      #pragma unroll
      for (int k = 0; k < K2; ++k) a0 = fmaf(wv[k], yw[k], a0);
      #pragma unroll
      for (int k = 0; k < K2; ++k) a1 = fmaf(wv[k], yw[1 + k], a1);
      #pragma unroll
      for (int k = 0; k < K2; ++k) a2 = fmaf(wv[k], yw[2 + k], a2);
      #pragma unroll
      for (int k = 0; k < K2; ++k) a3 = fmaf(wv[k], yw[3 + k], a3);
    }
    *(float4*)&yout[t0] = make_float4(a0, a1, a2, a3);
    s += a0; s2 += (double)a0 * a0;
    s += a1; s2 += (double)a1 * a1;
    s += a2; s2 += (double)a2 * a2;
    s += a3; s2 += (double)a3 * a3;
  }
}

__global__ __launch_bounds__(256) void k_mid(
    const float* __restrict__ x,
    const float* __restrict__ w11, const float* __restrict__ w12,
    const float* __restrict__ w13, const float* __restrict__ w14,
    const float* __restrict__ b1, const float* __restrict__ g1,
    const float* __restrict__ be1,
    const double* __restrict__ partS1, const double* __restrict__ partQ1,
    const float* __restrict__ w21, const float* __restrict__ w22,
    const float* __restrict__ w23, const float* __restrict__ w24,
    const float* __restrict__ b2,
    float* __restrict__ y2raw,
    double* __restrict__ partS, double* __restrict__ partQ,
    const float* __restrict__ cbs, short* __restrict__ dh,
    float* __restrict__ cbn)
{
  __shared__ float sx[T_IN];
  __shared__ float sy[CCH*100];
  __shared__ float sstat[8];
  __shared__ double rs[256], rq[256];
  __shared__ short S[25][65][8];

  const int bid = blockIdx.x;
  const int tid = threadIdx.x;

  if (bid >= 4096) {
    cvt_body(bid - 4096, 4, cbs, dh, cbn, S);
    return;
  }

  const int br = bid >> 10;
  const int b  = (bid >> 7) & 7;
  const int na = bid & 127;
  const int c  = tid >> 5;
  const int tl = tid & 31;
  const int wid = tid >> 6;
  const int l = tid & 63;
  const float* w1 = (br==0) ? w11 : (br==1) ? w12 : (br==2) ? w13 : w14;
  const float* w2 = (br==0) ? w21 : (br==1) ? w22 : (br==2) ? w23 : w24;

  if (tid < T_IN) sx[tid] = x[((size_t)b*NAA + na)*T_IN + tid];

  {
    int base = (((br*BB + b)*4 + wid) << 7);
    double a  = partS1[base + l] + partS1[base + 64 + l];
    double qn = partQ1[base + l] + partQ1[base + 64 + l];
    #pragma unroll
    for (int m = 32; m >= 1; m >>= 1) {
      a  += __shfl_xor(a, m);
      qn += __shfl_xor(qn, m);
    }
    if (l == 0) {
      double mean = a / 51200.0;            // 2*128*200
      double var  = qn / 51200.0 - mean*mean;
      sstat[wid*2]     = (float)mean;
      sstat[wid*2 + 1] = (float)(1.0 / sqrt(var + 1e-5));
    }
  }
  __syncthreads();

  const float bias1 = b1[br*CCH + c];
  const float fm  = sstat[(c>>1)*2];
  const float rst = sstat[(c>>1)*2 + 1];
  const float gm = g1[br*CCH + c], bt = be1[br*CCH + c];
  const float bias2 = b2[br*CCH + c];
  float* yout = y2raw + ((((size_t)br*BB + b)*CCH + c)*NAA + na)*100;

  double s = 0.0, s2 = 0.0;
  switch (br) {
    case 0: mid_body<21,9>(sx, sy, w1, w2, bias1, fm, rst, gm, bt, bias2, c, tl, yout, s, s2); break;
    case 1: mid_body<15,7>(sx, sy, w1, w2, bias1, fm, rst, gm, bt, bias2, c, tl, yout, s, s2); break;
    case 2: mid_body<9,5> (sx, sy, w1, w2, bias1, fm, rst, gm, bt, bias2, c, tl, yout, s, s2); break;
    default: mid_body<5,3>(sx, sy, w1, w2, bias1, fm, rst, gm, bt, bias2, c, tl, yout, s, s2); break;
  }

  rs[tid] = s; rq[tid] = s2;
  __syncthreads();
  for (int off = 32; off > 0; off >>= 1) {
    if ((tid & 63) < off) { rs[tid] += rs[tid+off]; rq[tid] += rq[tid+off]; }
    __syncthreads();
  }
  if ((tid & 63) == 0) {
    int g = tid >> 6;
    int pi = (((br*BB + b)*4 + g) << 7) + na;
    partS[pi] = rs[tid]; partQ[pi] = rq[tid];
  }
}

// ---------------- K5: inline stats2 + GN2 + GELU + pool4 + transpose (+ padzero) ----------------
__global__ __launch_bounds__(256) void k_tail(
    const float* __restrict__ y2raw, const float* __restrict__ g2,
    const float* __restrict__ be2,
    const double* __restrict__ partS2, const double* __restrict__ partQ2,
    float* __restrict__ res, short* __restrict__ resh)
{
  const int tid = threadIdx.x;
  int idx = blockIdx.x * 256 + tid;
  int c  = idx & 7;
  int tp = (idx >> 3) % 25;
  int na = (idx / 200) & 127;
  int b  = (idx / 25600) & 7;
  int br = idx / 204800;
  const int wid = tid >> 6, l = tid & 63;

  if (idx < NBR*3*ROWS*8) {
    int pos = idx & 7;
    int prow = (idx >> 3) & 1023;
    int r2  = idx >> 13;
    int pbr = r2 / 3, kgp = r2 - pbr*3;
    resh[(((size_t)pbr*NKG + 25 + kgp)*ROWS + prow)*8 + pos] = 0;
  }

  __shared__ float sstat[8];
  {
    int base = (((br*BB + b)*4 + wid) << 7);
    double a  = partS2[base + l] + partS2[base + 64 + l];
    double qn = partQ2[base + l] + partQ2[base + 64 + l];
    #pragma unroll
    for (int m = 32; m >= 1; m >>= 1) {
      a  += __shfl_xor(a, m);
      qn += __shfl_xor(qn, m);
    }
    if (l == 0) {
      double mean = a / 25600.0;            // 2*128*100
      double var  = qn / 25600.0 - mean*mean;
      sstat[wid*2]     = (float)mean;
      sstat[wid*2 + 1] = (float)(1.0 / sqrt(var + 1e-5));
    }
  }
  __syncthreads();

  int g = c >> 1;
  float fm  = sstat[g*2];
  float rst = sstat[g*2 + 1];
  float gm = g2[br*CCH + c], bt = be2[br*CCH + c];
  float4 v = *(const float4*)&y2raw[((((size_t)br*BB + b)*CCH + c)*NAA + na)*100 + 4*tp];
  float sum4 = 0.f;
  #pragma unroll
  for (int h = 0; h < 4; ++h) {
    float xv = (h==0) ? v.x : (h==1) ? v.y : (h==2) ? v.z : v.w;
    float xn = (xv - fm) * rst * gm + bt;
    sum4 += 0.5f * xn * (1.0f + erff(xn * 0.70710678118654752440f));
  }
  float val = 0.25f * sum4;
  int row = b*NAA + na;
  res[((size_t)br*ROWS + row)*DD + tp*8 + c] = val;
  resh[(((size_t)br*NKG + tp)*ROWS + row)*8 + c] = (short)f2bf(val);
}

// ---------------- standalone cvt (small-ws fallback, one q) ----------------
__global__ __launch_bounds__(256) void k_cvt_cb(
    const float* __restrict__ cbs, int q,
    short* __restrict__ dh, float* __restrict__ cbn)
{
  __shared__ short S[25][65][8];
  const int blk = blockIdx.x;
  const int vt = blk & 127;
  const int br = blk >> 7;
  const int tid = threadIdx.x;
  const int row = tid >> 2, fq = tid & 3;
  const int v0 = vt*64;
  const float* srow = cbs + ((size_t)(br*NQ + q)*NV + v0 + row)*DD;

  float s = 0.f;
  for (int j = 0; j < 13; ++j) {
    int f4 = fq + 4*j;
    if (f4 < 50) {
      float4 f = *(const float4*)&srow[4*f4];
      s += f.x*f.x + f.y*f.y + f.z*f.z + f.w*f.w;
      *(short4*)&S[f4>>1][row][(f4&1)*4] =
          make_short4((short)f2bf(f.x), (short)f2bf(f.y),
                      (short)f2bf(f.z), (short)f2bf(f.w));
    }
  }
  s += __shfl_xor(s, 1);
  s += __shfl_xor(s, 2);
  if (fq == 0) cbn[(size_t)(br*NQ + q)*NV + v0 + row] = s;
  __syncthreads();

  for (int u = tid; u < NKG*64*2; u += 256) {
    int kg = u >> 7;
    int rem = u & 127;
    int v = rem >> 1, pos = (rem & 1)*4;
    short4 val = (kg < 25) ? *(const short4*)&S[kg][v][pos]
                           : make_short4(0,0,0,0);
    *(short4*)&dh[(((size_t)br*NKG + kg)*NV + v0 + v)*8 + pos] = val;
  }
}

// ---------------- MFMA approx-distance GEMM + packed-key top-2 epilogue ----------------
// grid 2048, 256 threads (4 waves, wave tile 64x64); XCD-pinned vb
// counted vmcnt(6) pipeline; B LDS plane-padded to 130 rows
__global__ __launch_bounds__(256) void k_gemm(
    const short* __restrict__ resh, const short* __restrict__ cbh,
    const float* __restrict__ cbn, int q,
    unsigned* __restrict__ candk)
{
  __shared__ short S[2][4][130][8];  // 33.3 KB

  const int p = blockIdx.x;
  const int x = p & 7;               // XCD (dispatch round-robin)
  const int sIdx = p >> 3;
  const int br = sIdx >> 6;
  const int rb = (sIdx >> 3) & 7;
  const int vb = x*8 + (sIdx & 7);   // XCD x owns vb in [8x, 8x+8)
  const int tid = threadIdx.x;
  const int w = tid >> 6;
  const int l = tid & 63;
  const int wr = w >> 1, wc = w & 1;
  const int kgl = l >> 4, fr = l & 15;

  f32x4 acc[4][4];
  #pragma unroll
  for (int i = 0; i < 4; ++i)
    #pragma unroll
    for (int j = 0; j < 4; ++j)
      acc[i][j] = (f32x4){0.f, 0.f, 0.f, 0.f};

  short8 aA[2][4];   // A fragments, double-buffered in regs

  // per wave per stage: 4 A-reg loads + 2 gld16 = 6 vmem ops
  #define STAGE(nb, ks)                                                         \
    {                                                                           \
      _Pragma("unroll")                                                         \
      for (int i = 0; i < 4; ++i)                                               \
        aA[nb][i] = *(const short8*)&resh[                                      \
          (((size_t)br*NKG + (ks)*4 + kgl)*ROWS + rb*128 + wr*64 + i*16 + fr)*8]; \
      _Pragma("unroll")                                                         \
      for (int t = 0; t < 2; ++t) {                                             \
        int u = (w << 1) | t;                                                   \
        int kg = u >> 1, wh = u & 1;                                            \
        gld16(cbh + (((size_t)br*NKG + (ks)*4 + kg)*NV + vb*128 + wh*64 + l)*8, \
              &S[nb][kg][wh*64][0]);                                            \
      }                                                                         \
    }

  STAGE(0, 0);

  #pragma unroll
  for (int ks = 0; ks < 7; ++ks) {
    const int cur = ks & 1, nxt = cur ^ 1;
    if (ks < 6) {
      STAGE(nxt, ks + 1);
      asm volatile("s_waitcnt vmcnt(6)" ::: "memory");  // stage(ks) complete
    } else {
      asm volatile("s_waitcnt vmcnt(0)" ::: "memory");
    }
    __builtin_amdgcn_s_barrier();

    short8 bh[4];
    #pragma unroll
    for (int j = 0; j < 4; ++j)
      bh[j] = *(const short8*)&S[cur][kgl][wc*64 + j*16 + fr][0];
    #pragma unroll
    for (int i = 0; i < 4; ++i)
      #pragma unroll
      for (int j = 0; j < 4; ++j)
        acc[i][j] = __builtin_amdgcn_mfma_f32_16x16x32_bf16(aA[cur][i], bh[j], acc[i][j], 0, 0, 0);

    asm volatile("" ::: "memory");
    __builtin_amdgcn_s_barrier();   // all waves done reading S[cur] before overwrite
  }

  // epilogue: packed-key top-2 per (row, 64-col half)
  const float* cn = cbn + (size_t)(br*NQ + q)*NV;
  float nj[4]; int vgj[4];
  #pragma unroll
  for (int j = 0; j < 4; ++j) {
    vgj[j] = vb*128 + wc*64 + j*16 + fr;
    nj[j] = 0.5f * cn[vgj[j]];
  }
  #pragma unroll
  for (int i = 0; i < 4; ++i) {
    #pragma unroll
    for (int reg = 0; reg < 4; ++reg) {
      unsigned k0 = skey(nj[0] - acc[i][0][reg], vgj[0]);
      unsigned k1 = skey(nj[1] - acc[i][1][reg], vgj[1]);
      unsigned k2 = skey(nj[2] - acc[i][2][reg], vgj[2]);
      unsigned k3 = skey(nj[3] - acc[i][3][reg], vgj[3]);
      unsigned a = umn(k0, k1), b = umx(k0, k1);
      unsigned c = umn(k2, k3), d = umx(k2, k3);
      unsigned c1 = umn(a, c);
      unsigned c2 = umn(umx(a, c), umn(b, d));
      #pragma unroll
      for (int m = 1; m <= 8; m <<= 1) {
        unsigned o1 = __shfl_xor(c1, m);
        unsigned o2 = __shfl_xor(c2, m);
        unsigned t = umx(c1, o1);
        c1 = umn(c1, o1);
        c2 = umn(umn(t, c2), o2);
      }
      if (fr == 0) {
        int grow = br*ROWS + rb*128 + wr*64 + i*16 + kgl*4 + reg;
        size_t o = ((size_t)grow*64 + vb)*4 + wc*2;
        candk[o] = c1; candk[o+1] = c2;
      }
    }
  }
  #undef STAGE
}

// ---------------- wave-local top-8 select (keys) + exact f32 rescore + update ----------------
__global__ __launch_bounds__(256) void k_update3(
    const float* __restrict__ cbs, const float* __restrict__ cbn,
    const unsigned* __restrict__ candk,
    float* __restrict__ res, float* __restrict__ outq,
    float* __restrict__ outi, short* __restrict__ resh, int q)
{
  const int wid = threadIdx.x >> 6;
  const int lane = threadIdx.x & 63;
  const int r = blockIdx.x*4 + wid;   // 0..4095
  const int br = r >> 10;
  const int row = r & 1023;

  const unsigned* ck = candk + (size_t)r * 256;
  uint4 kk = *(const uint4*)&ck[4*lane];
  unsigned c0 = kk.x, c1 = kk.y, c2 = kk.z, c3 = kk.w;

  unsigned mykey = 0xFFFFFFFFu;
  #pragma unroll
  for (int t = 0; t < 8; ++t) {
    unsigned lm = umn(umn(c0, c1), umn(c2, c3));
    #pragma unroll
    for (int m = 1; m <= 32; m <<= 1)
      lm = umn(lm, __shfl_xor(lm, m));
    if (c0 == lm) c0 = 0xFFFFFFFFu;
    if (c1 == lm) c1 = 0xFFFFFFFFu;
    if (c2 == lm) c2 = 0xFFFFFFFFu;
    if (c3 == lm) c3 = 0xFFFFFFFFu;
    if ((lane >> 3) == t) mykey = lm;
  }
  const int mycand = (int)(mykey & 0x1FFFu);

  // exact rescore: 8 lanes per candidate
  const int kl = lane & 7;
  const float* cbrow = cbs + ((size_t)(br*NQ + q)*NV + mycand)*DD;
  const float* rrow0 = res + (size_t)r*DD;
  float dot = 0.f;
  #pragma unroll
  for (int u = 0; u < 7; ++u) {
    int f4 = kl + 8*u;
    if (f4 < 50) {
      float4 r4 = *(const float4*)&rrow0[4*f4];
      float4 c4 = *(const float4*)&cbrow[4*f4];
      dot = fmaf(r4.x, c4.x, dot);
      dot = fmaf(r4.y, c4.y, dot);
      dot = fmaf(r4.z, c4.z, dot);
      dot = fmaf(r4.w, c4.w, dot);
    }
  }
  dot += __shfl_xor(dot, 1);
  dot += __shfl_xor(dot, 2);
  dot += __shfl_xor(dot, 4);
  float dist = fmaf(-2.f, dot, cbn[(size_t)(br*NQ + q)*NV + mycand]);

  float bv = dist; int bi = mycand;
  #pragma unroll
  for (int m = 8; m <= 32; m <<= 1) {
    float ov = __shfl_xor(bv, m); int oi = __shfl_xor(bi, m);
    if (lexlt(ov, oi, bv, bi)) { bv = ov; bi = oi; }
  }

  if (lane == 0)
    outi[(((size_t)br*NQ + q)*BB + (row >> 7))*NAA + (row & 127)] = (float)bi;

  const float* c = cbs + ((size_t)(br*NQ + q)*NV + bi)*DD;
  float* rrow = res  + ((size_t)br*ROWS + row)*DD;
  float* qrow = outq + ((size_t)br*ROWS + row)*DD;
  if (lane < 50) {
    float4 cvv = *(const float4*)&c[4*lane];
    float4 r4 = *(const float4*)&rrow[4*lane];
    r4.x -= cvv.x; r4.y -= cvv.y; r4.z -= cvv.z; r4.w -= cvv.w;
    *(float4*)&rrow[4*lane] = r4;
    float4 qv;
    if (q == 0) {
      qv = cvv;
    } else {
      qv = *(const float4*)&qrow[4*lane];
      qv.x += cvv.x; qv.y += cvv.y; qv.z += cvv.z; qv.w += cvv.w;
    }
    *(float4*)&qrow[4*lane] = qv;

    *(short4*)&resh[(((size_t)br*NKG + (lane>>1))*ROWS + row)*8 + (lane&1)*4] =
        make_short4((short)f2bf(r4.x), (short)f2bf(r4.y),
                    (short)f2bf(r4.z), (short)f2bf(r4.w));
  }
}

extern "C" void kernel_launch(void* const* d_in, const int* in_sizes, int n_in,
                              void* d_out, int out_size, void* d_ws, size_t ws_size,
                              hipStream_t stream)
{
  const float* x   = (const float*)d_in[0];
  const float* w11 = (const float*)d_in[1];
  const float* w12 = (const float*)d_in[2];
  const float* w13 = (const float*)d_in[3];
  const float* w14 = (const float*)d_in[4];
  const float* b1  = (const float*)d_in[5];
  const float* g1  = (const float*)d_in[6];
  const float* be1 = (const float*)d_in[7];
  const float* w21 = (const float*)d_in[8];
  const float* w22 = (const float*)d_in[9];
  const float* w23 = (const float*)d_in[10];
  const float* w24 = (const float*)d_in[11];
  const float* b2  = (const float*)d_in[12];
  const float* g2  = (const float*)d_in[13];
  const float* be2 = (const float*)d_in[14];
  const float* cbs = (const float*)d_in[15];

  // workspace layout
  char* wsb = (char*)d_ws;
  double* partS1 = (double*)wsb;
  double* partQ1 = partS1 + 16384;
  double* partS2 = partQ1 + 16384;
  double* partQ2 = partS2 + 16384;
  float* fbase = (float*)(partQ2 + 16384);
  float* y2raw = fbase;                                // 3,276,800
  float* res   = y2raw + 3276800;                      // 819,200
  float* cbn   = res + 819200;                         // 262,144
  unsigned* candk = (unsigned*)(cbn + 262144);         // 1,048,576 u32
  short* resh  = (short*)(candk + 1048576);            // 917,504 shorts
  short* cbh   = resh + 917504;                        // CBQSH * (big ? 8 : 1)
  const size_t base_bytes = (char*)cbh - wsb;
  const bool big = ws_size >= base_bytes + CBQSH*8*sizeof(short) + 1024;

  float* outq = (float*)d_out;         // [4][8][128][200]
  float* outi = outq + 819200;         // [4][8][8][128] (float-encoded indices)

  // frontend (+ cvt overlapped into the two compute-heavy kernels when big)
  if (big) {
    k_front1<<<4096 + 2048, 256, 0, stream>>>(x, w11, w12, w13, w14, b1,
                                              partS1, partQ1, cbs, cbh, cbn);
    k_mid<<<4096 + 2048, 256, 0, stream>>>(x, w11, w12, w13, w14, b1, g1, be1,
                                           partS1, partQ1,
                                           w21, w22, w23, w24, b2, y2raw,
                                           partS2, partQ2, cbs, cbh, cbn);
  } else {
    k_conv1_stats<<<4096, 256, 0, stream>>>(x, w11, w12, w13, w14, b1, partS1, partQ1);
    k_mid<<<4096, 256, 0, stream>>>(x, w11, w12, w13, w14, b1, g1, be1,
                                    partS1, partQ1,
                                    w21, w22, w23, w24, b2, y2raw,
                                    partS2, partQ2, cbs, cbh, cbn);
  }
  k_tail<<<3200, 256, 0, stream>>>(y2raw, g2, be2, partS2, partQ2, res, resh);

  for (int q = 0; q < NQ; ++q) {
    if (!big)
      k_cvt_cb<<<NBR*128, 256, 0, stream>>>(cbs, q, cbh, cbn);
    const short* cbh_q = cbh + (big ? (size_t)q*CBQSH : 0);
    k_gemm<<<2048, 256, 0, stream>>>(resh, cbh_q, cbn, q, candk);
    k_update3<<<1024, 256, 0, stream>>>(cbs, cbn, candk, res, outq, outi, resh, q);
  }
}